// Round 5
// baseline (883.055 us; speedup 1.0000x reference)
//
#include <hip/hip_runtime.h>
#include <hip/hip_cooperative_groups.h>
#include <math.h>

namespace cg = cooperative_groups;

// ---------------------------------------------------------------------------
// SocialLstm: T=24, N=2048, INPUT_DIM=2, HIDDEN=64, MEDIATE=128, SOCIAL=64,
// OUT_DIM=2, N_SIZE=2, CELL=0.3, T_obs=9, T_pred=19, WIN=9.
//
// R5: single persistent cooperative kernel (128 blocks x 512 thr). R4 was
// launch/serialization-bound (~12us per 2us-of-work k_step). Now: W frags
// register-resident (loaded once), c-state in registers, all step constants
// in LDS, out[t-2] feedback block-local, grid.sync() between steps.
// Prologue absorbs k_init (We fold, tail zero) + k_gridmatch (blocks 0..19).
// MFMA hi/lo bf16 split (ZhWh+ZlWh+ZhWl) verified R3/R4, absmax 1.95e-3.
// ---------------------------------------------------------------------------

#define N_AG   2048
#define STEPS  20
#define CAP    12

typedef short short8 __attribute__((ext_vector_type(8)));
typedef float f32x4  __attribute__((ext_vector_type(4)));
union FU { uint4 q; short8 v; };

__device__ __forceinline__ unsigned short bf16rne(float x) {
    unsigned u = __float_as_uint(x);
    unsigned r = (u + 0x7fff + ((u >> 16) & 1)) >> 16;
    return (unsigned short)r;
}

__device__ __forceinline__ int khash(int k) {
    return (int)(((unsigned)k * 2654435761u) >> 21);   // 11-bit bucket
}

struct KP {
    const float *X, *masks, *h_in, *c_in;
    const float *Win, *bin, *Wsoc, *bsoc, *Wih, *Whh, *bih, *bhh, *Wout, *bout;
    float *out, *hA, *hB, *Wef;
    int *mcnt, *midx;
};

__global__ __launch_bounds__(512, 2) void k_persist(KP p)
{
    cg::grid_group gg = cg::this_grid();

    __shared__ __align__(16) union LU {
        struct { short zsh[4096]; short zsl[4096]; float gbuf[16][258]; } s;
        struct { int kk[N_AG]; int head[N_AG]; int nxt[N_AG]; float red[512]; } m;
    } u;
    __shared__ float cvs[16][64];
    __shared__ float hs[16][68];          // row stride 68 -> 16B-aligned rows
    __shared__ float sX[11][16][2];
    __shared__ float sMask[STEPS][16];
    __shared__ int   sCnt[STEPS][16];
    __shared__ float sWin[256], sBin[128], sBc[256], sBsoc[64], sWout[128], sBout[2];
    __shared__ float olocal[2][16][2];

    const int tid   = threadIdx.x;
    const int bx    = blockIdx.x;
    const int wbase = bx * 16;
    const int wv    = tid >> 6, lane = tid & 63;
    const int mA    = lane & 15, quad = lane >> 4;
    const int nt0   = 2 * wv;

    // =================== prologue ===================
    // per-block constant stashes
    if (tid < 256) { sWin[tid] = p.Win[tid]; sBc[tid] = p.bih[tid] + p.bhh[tid]; }
    if (tid < 128) { sBin[tid] = p.bin[tid]; sWout[tid] = p.Wout[tid]; }
    if (tid < 64)  sBsoc[tid] = p.bsoc[tid];
    if (tid < 2)   sBout[tid] = p.bout[tid];
    if (tid < 352) { int tt = tid / 32, r = tid % 32;
                     sX[tt][r >> 1][r & 1] = p.X[tt * (N_AG * 2) + (wbase + (r >> 1)) * 2 + (r & 1)]; }
    if (tid < 320) { int tt = tid / 16, m2 = tid % 16;
                     sMask[tt][m2] = p.masks[tt * N_AG + wbase + m2]; }

    // own h (LDS) + c (registers)
    float c0, c1;
    {
        int m0 = tid >> 6,        h0i = tid & 63;
        int m1 = (tid >> 6) + 8;
        hs[m0][h0i] = p.h_in[(wbase + m0) * 64 + h0i];
        hs[m1][h0i] = p.h_in[(wbase + m1) * 64 + h0i];
        c0 = p.c_in[(wbase + m0) * 64 + h0i];
        c1 = p.c_in[(wbase + m1) * 64 + h0i];
    }

    // register-resident W fragments (hi/lo split), loaded once
    FU wh[2][8], wl[2][8];
    #pragma unroll
    for (int e = 0; e < 2; e++) {
        int g = (nt0 + e) * 16 + mA;
        #pragma unroll
        for (int kt = 0; kt < 8; kt++) {
            int k0 = kt * 32 + quad * 8;        // 8-run never crosses the 192 boundary
            const float* src = (k0 < 192) ? (p.Wih + g * 192 + k0)
                                          : (p.Whh + g * 64 + (k0 - 192));
            unsigned uh[4], ul[4];
            #pragma unroll
            for (int w = 0; w < 4; w++) {
                float a = src[2 * w], b = src[2 * w + 1];
                unsigned short ha = bf16rne(a), hb = bf16rne(b);
                float fa = __uint_as_float(((unsigned)ha) << 16);
                float fb = __uint_as_float(((unsigned)hb) << 16);
                unsigned short la = bf16rne(a - fa), lb = bf16rne(b - fb);
                uh[w] = (unsigned)ha | ((unsigned)hb << 16);
                ul[w] = (unsigned)la | ((unsigned)lb << 16);
            }
            wh[e][kt].q = make_uint4(uh[0], uh[1], uh[2], uh[3]);
            wl[e][kt].q = make_uint4(ul[0], ul[1], ul[2], ul[3]);
        }
    }

    // specialty blocks: 0..19 hash match per step, 20 We fold, 21..52 tail zero
    if (bx < 20) {
        const int t = bx;
        const float* Xt = p.X + t * N_AG * 2;
        float mnx = 1e30f, mny = 1e30f;
        for (int i = tid; i < N_AG; i += 512) {
            mnx = fminf(mnx, Xt[2 * i]);
            mny = fminf(mny, Xt[2 * i + 1]);
        }
        u.m.red[tid] = mnx; __syncthreads();
        for (int s = 256; s > 0; s >>= 1) { if (tid < s) u.m.red[tid] = fminf(u.m.red[tid], u.m.red[tid + s]); __syncthreads(); }
        float ltx = u.m.red[0]; __syncthreads();
        u.m.red[tid] = mny; __syncthreads();
        for (int s = 256; s > 0; s >>= 1) { if (tid < s) u.m.red[tid] = fminf(u.m.red[tid], u.m.red[tid + s]); __syncthreads(); }
        float lty = u.m.red[0]; __syncthreads();
        ltx -= 1.2f;   // margin = 2*N_SIZE*CELL
        lty -= 1.2f;

        for (int i = tid; i < N_AG; i += 512) {
            float m = p.masks[t * N_AG + i];
            int px = (int)floorf((Xt[2 * i]     - ltx) / 0.3f);
            int py = (int)floorf((Xt[2 * i + 1] - lty) / 0.3f);
            int im = (int)m;
            px *= im; py *= im;
            u.m.kk[i] = px * 65536 + py;   // masked -> 0; real agents px,py >= 4
            u.m.head[i] = -1;
        }
        __syncthreads();
        for (int j = tid; j < N_AG; j += 512) {
            int kj = u.m.kk[j];
            if (kj != 0) u.m.nxt[j] = atomicExch(&u.m.head[khash(kj)], j);
        }
        __syncthreads();
        for (int i = tid; i < N_AG; i += 512) {
            int ki = u.m.kk[i];
            int cnt = 0;
            int base = (t * N_AG + i) * CAP;
            if (ki != 0) {
                int tkey = ki - 65537;
                int lst[CAP];
                for (int j = u.m.head[khash(tkey)]; j >= 0; j = u.m.nxt[j]) {
                    if (u.m.kk[j] == tkey) { if (cnt < CAP) lst[cnt] = j; cnt++; }
                }
                if (cnt > CAP) cnt = CAP;
                for (int a = 1; a < cnt; a++) {        // ascending j = ref sum order
                    int v = lst[a]; int b = a - 1;
                    while (b >= 0 && lst[b] > v) { lst[b + 1] = lst[b]; b--; }
                    lst[b + 1] = v;
                }
                for (int a = 0; a < cnt; a++) p.midx[base + a] = lst[a];
            }
            p.mcnt[t * N_AG + i] = cnt;
        }
        __syncthreads();           // done with u.m before step loop reuses u.s
    } else if (bx == 20) {
        for (int i = tid; i < 4096; i += 512) {
            int s = i >> 6, k = i & 63;
            float a = 0.f;
            #pragma unroll
            for (int w = 0; w < 9; w++) a += p.Wsoc[s * 576 + w * 64 + k];
            p.Wef[i] = a;
        }
    } else if (bx >= 21 && bx < 53) {
        p.out[20 * N_AG * 2 + (bx - 21) * 512 + tid] = 0.f;   // frames 20..23
    }

    __threadfence();
    gg.sync();

    // stash per-step match counts (written by blocks 0..19)
    if (tid < 320) { int tt = tid / 16, m2 = tid % 16;
                     sCnt[tt][m2] = p.mcnt[tt * N_AG + wbase + m2]; }
    __syncthreads();

    // =================== recurrence ===================
    #pragma unroll 1
    for (int t = 0; t < STEPS; t++) {
        float* hw       = (t & 1) ? p.hB : p.hA;
        const float* hr = (t == 0) ? p.h_in : ((t & 1) ? p.hA : p.hB);

        // ---- phase A: social cell gather (32 thr/agent; rare) ----
        {
            int m = tid >> 5, j = tid & 31;
            int cnt = sCnt[t][m];
            if (cnt > 0) {
                int base = (t * N_AG + wbase + m) * CAP;
                float a0 = 0.f, a1 = 0.f;
                for (int n = 0; n < cnt; n++) {
                    int r = p.midx[base + n];
                    a0 += hr[r * 64 + j];
                    a1 += hr[r * 64 + j + 32];
                }
                cvs[m][j] = a0; cvs[m][j + 32] = a1;
            }
        }
        __syncthreads();

        // ---- phase B: z-build -> bf16 hi/lo planes in A-frag order ----
        {
            int m = tid >> 5, s5 = tid & 31;
            float px, py;
            if (t <= 10) { px = sX[t][m][0];          py = sX[t][m][1]; }
            else         { px = olocal[t & 1][m][0];  py = olocal[t & 1][m][1]; }
            int cnt = sCnt[t][m];
            int q8 = s5 >> 3, jj = s5 & 7;
            #pragma unroll
            for (int uu = 0; uu < 8; uu++) {
                int c = 32 * uu + s5;
                float v;
                if (uu < 4) {
                    v = fmaxf(sWin[2 * c] * px + sWin[2 * c + 1] * py + sBin[c], 0.f);
                } else if (uu < 6) {
                    int s = c - 128;
                    float acc = sBsoc[s];
                    if (cnt > 0) {                    // cnt>0 implies mask==1
                        const float* wp = p.Wef + s * 64;
                        #pragma unroll 4
                        for (int k = 0; k < 64; k += 4) {
                            float4 c4 = *(const float4*)&cvs[m][k];
                            float4 w4 = *(const float4*)&wp[k];
                            acc += c4.x * w4.x + c4.y * w4.y + c4.z * w4.z + c4.w * w4.w;
                        }
                    }
                    v = fmaxf(acc, 0.f);
                } else {
                    v = hs[m][c - 192];
                }
                unsigned short h = bf16rne(v);
                float fh = __uint_as_float(((unsigned)h) << 16);
                unsigned short l = bf16rne(v - fh);
                int fi = ((uu * 4 + q8) * 16 + m) * 8 + jj;
                u.s.zsh[fi] = (short)h;
                u.s.zsl[fi] = (short)l;
            }
        }
        __syncthreads();

        // ---- phase C: GEMM with register-resident W ----
        {
            const uint4* zhp = (const uint4*)u.s.zsh;
            const uint4* zlp = (const uint4*)u.s.zsl;
            f32x4 a0v = {0.f, 0.f, 0.f, 0.f};
            f32x4 a1v = {0.f, 0.f, 0.f, 0.f};
            #pragma unroll
            for (int kt = 0; kt < 8; kt++) {
                int fi = (kt * 4 + quad) * 16 + mA;
                FU az, bz;
                az.q = zhp[fi];
                bz.q = zlp[fi];
                a0v = __builtin_amdgcn_mfma_f32_16x16x32_bf16(az.v, wh[0][kt].v, a0v, 0, 0, 0);
                a1v = __builtin_amdgcn_mfma_f32_16x16x32_bf16(az.v, wh[1][kt].v, a1v, 0, 0, 0);
                a0v = __builtin_amdgcn_mfma_f32_16x16x32_bf16(bz.v, wh[0][kt].v, a0v, 0, 0, 0);
                a1v = __builtin_amdgcn_mfma_f32_16x16x32_bf16(bz.v, wh[1][kt].v, a1v, 0, 0, 0);
                a0v = __builtin_amdgcn_mfma_f32_16x16x32_bf16(az.v, wl[0][kt].v, a0v, 0, 0, 0);
                a1v = __builtin_amdgcn_mfma_f32_16x16x32_bf16(az.v, wl[1][kt].v, a1v, 0, 0, 0);
            }
            #pragma unroll
            for (int r = 0; r < 4; r++) {
                int row = quad * 4 + r;           // agent slot
                u.s.gbuf[row][nt0 * 16 + mA]       = a0v[r];
                u.s.gbuf[row][(nt0 + 1) * 16 + mA] = a1v[r];
            }
        }
        __syncthreads();

        // ---- phase D: LSTM elementwise; c in registers ----
        {
            int m0 = tid >> 6, hid = tid & 63;
            {
                float gi = u.s.gbuf[m0][hid]       + sBc[hid];
                float gf = u.s.gbuf[m0][64 + hid]  + sBc[64 + hid];
                float gR = u.s.gbuf[m0][128 + hid] + sBc[128 + hid];
                float go = u.s.gbuf[m0][192 + hid] + sBc[192 + hid];
                float si = 1.f / (1.f + expf(-gi));
                float sf = 1.f / (1.f + expf(-gf));
                float so = 1.f / (1.f + expf(-go));
                float cn = sf * c0 + si * tanhf(gR);
                float hn = so * tanhf(cn);
                c0 = cn;
                hs[m0][hid] = hn;
                hw[(wbase + m0) * 64 + hid] = hn;
            }
            int m1 = m0 + 8;
            {
                float gi = u.s.gbuf[m1][hid]       + sBc[hid];
                float gf = u.s.gbuf[m1][64 + hid]  + sBc[64 + hid];
                float gR = u.s.gbuf[m1][128 + hid] + sBc[128 + hid];
                float go = u.s.gbuf[m1][192 + hid] + sBc[192 + hid];
                float si = 1.f / (1.f + expf(-gi));
                float sf = 1.f / (1.f + expf(-gf));
                float so = 1.f / (1.f + expf(-go));
                float cn = sf * c1 + si * tanhf(gR);
                float hn = so * tanhf(cn);
                c1 = cn;
                hs[m1][hid] = hn;
                hw[(wbase + m1) * 64 + hid] = hn;
            }
        }
        __syncthreads();

        // ---- phase E: out = (h @ W_out.T + b_out) * mask ----
        if (tid < 32) {
            int m = tid >> 1, d = tid & 1;
            float acc = sBout[d];
            #pragma unroll 4
            for (int k = 0; k < 64; k += 4) {
                float4 h4 = *(const float4*)&hs[m][k];
                float4 w4 = *(const float4*)&sWout[d * 64 + k];
                acc += h4.x * w4.x + h4.y * w4.y + h4.z * w4.z + h4.w * w4.w;
            }
            float val = acc * sMask[t][m];
            p.out[(t * N_AG + wbase + m) * 2 + d] = val;
            olocal[t & 1][m][d] = val;
        }

        __threadfence();
        gg.sync();
    }
}

// ---------------------------------------------------------------------------
extern "C" void kernel_launch(void* const* d_in, const int* in_sizes, int n_in,
                              void* d_out, int out_size, void* d_ws, size_t ws_size,
                              hipStream_t stream)
{
    KP kp;
    kp.X     = (const float*)d_in[0];
    kp.masks = (const float*)d_in[1];
    kp.h_in  = (const float*)d_in[2];
    kp.c_in  = (const float*)d_in[3];
    // d_in[4] = Y (unused), d_in[5] = T_obs (=9), d_in[6] = T_pred (=19)
    kp.Win   = (const float*)d_in[7];
    kp.bin   = (const float*)d_in[8];
    kp.Wsoc  = (const float*)d_in[9];
    kp.bsoc  = (const float*)d_in[10];
    kp.Wih   = (const float*)d_in[11];
    kp.Whh   = (const float*)d_in[12];
    kp.bih   = (const float*)d_in[13];
    kp.bhh   = (const float*)d_in[14];
    kp.Wout  = (const float*)d_in[15];
    kp.bout  = (const float*)d_in[16];
    kp.out   = (float*)d_out;

    float* ws = (float*)d_ws;
    kp.hA   = ws;                          // 131072
    kp.hB   = kp.hA + 131072;              // 131072
    kp.Wef  = kp.hB + 131072;              // 4096
    kp.mcnt = (int*)(kp.Wef + 4096);       // 20*2048
    kp.midx = kp.mcnt + STEPS * N_AG;      // 20*2048*CAP

    void* args[] = { &kp };
    hipLaunchCooperativeKernel((void*)k_persist, dim3(128), dim3(512), args, 0, stream);
}

// Round 6
// 271.667 us; speedup vs baseline: 3.2505x; 3.2505x over previous
//
#include <hip/hip_runtime.h>
#include <math.h>

// ---------------------------------------------------------------------------
// SocialLstm: T=24, N=2048, INPUT_DIM=2, HIDDEN=64, MEDIATE=128, SOCIAL=64,
// OUT_DIM=2, N_SIZE=2, CELL=0.3, T_obs=9, T_pred=19, WIN=9.
//
// R6: persistent cooperative kernel WITHOUT grid.sync (R5: 21 syncs x ~37us
// of L2-flush barrier = 790us). Cross-block h exchange now point-to-point:
// producers publish per-step h into hist[t] via relaxed agent-scope atomic
// stores (bypass non-coherent XCD L2s), __syncthreads() drains vmcnt, then
// one relaxed-atomic flag[t][block]=t+1. Consumers (only ~12% of agents have
// matches) spin on the specific producer's flag then atomic-load h words.
// Flag value t+1 never equals ws poison 0xAAAAAAAA -> no pre-zero needed.
// gridmatch/We-fold/tail-zero moved to k_pre (kernel boundary = coherence).
// MFMA hi/lo bf16 split (ZhWh+ZlWh+ZhWl) verified R3-R5, absmax 1.95e-3.
// ---------------------------------------------------------------------------

#define N_AG   2048
#define STEPS  20
#define CAP    12

typedef short short8 __attribute__((ext_vector_type(8)));
typedef float f32x4  __attribute__((ext_vector_type(4)));
union FU { uint4 q; short8 v; };

__device__ __forceinline__ unsigned short bf16rne(float x) {
    unsigned u = __float_as_uint(x);
    unsigned r = (u + 0x7fff + ((u >> 16) & 1)) >> 16;
    return (unsigned short)r;
}

__device__ __forceinline__ int khash(int k) {
    return (int)(((unsigned)k * 2654435761u) >> 21);   // 11-bit bucket
}

// ---------------------------------------------------------------------------
// k_pre: blocks 0..19 = per-step hash match; block 20 = We fold;
// blocks 21..52 = zero output tail frames 20..23.
// ---------------------------------------------------------------------------
__global__ __launch_bounds__(512) void k_pre(
    const float* __restrict__ X, const float* __restrict__ masks,
    const float* __restrict__ Wsoc,
    float* __restrict__ Wef, int* __restrict__ mcnt, int* __restrict__ midx,
    float* __restrict__ otail)
{
    const int bx = blockIdx.x, tid = threadIdx.x;

    if (bx >= 21) {                 // tail zero: 32 blocks x 512 = 16384
        otail[(bx - 21) * 512 + tid] = 0.f;
        return;
    }
    if (bx == 20) {                 // We fold: We[s][k] = sum_w Wsoc[s][w*64+k]
        for (int i = tid; i < 4096; i += 512) {
            int s = i >> 6, k = i & 63;
            float a = 0.f;
            #pragma unroll
            for (int w = 0; w < 9; w++) a += Wsoc[s * 576 + w * 64 + k];
            Wef[i] = a;
        }
        return;
    }

    // hash match for step t = bx
    __shared__ int kk[N_AG];
    __shared__ int head[N_AG];
    __shared__ int nxt[N_AG];
    __shared__ float red[512];
    const int t = bx;
    const float* Xt = X + t * N_AG * 2;

    float mnx = 1e30f, mny = 1e30f;
    for (int i = tid; i < N_AG; i += 512) {
        mnx = fminf(mnx, Xt[2 * i]);
        mny = fminf(mny, Xt[2 * i + 1]);
    }
    red[tid] = mnx; __syncthreads();
    for (int s = 256; s > 0; s >>= 1) { if (tid < s) red[tid] = fminf(red[tid], red[tid + s]); __syncthreads(); }
    float ltx = red[0]; __syncthreads();
    red[tid] = mny; __syncthreads();
    for (int s = 256; s > 0; s >>= 1) { if (tid < s) red[tid] = fminf(red[tid], red[tid + s]); __syncthreads(); }
    float lty = red[0]; __syncthreads();
    ltx -= 1.2f;   // margin = 2*N_SIZE*CELL
    lty -= 1.2f;

    for (int i = tid; i < N_AG; i += 512) {
        float m = masks[t * N_AG + i];
        int px = (int)floorf((Xt[2 * i]     - ltx) / 0.3f);
        int py = (int)floorf((Xt[2 * i + 1] - lty) / 0.3f);
        int im = (int)m;
        px *= im; py *= im;
        kk[i] = px * 65536 + py;    // masked -> 0; real agents have px,py >= 4
        head[i] = -1;
    }
    __syncthreads();
    for (int j = tid; j < N_AG; j += 512) {
        int kj = kk[j];
        if (kj != 0) nxt[j] = atomicExch(&head[khash(kj)], j);
    }
    __syncthreads();
    for (int i = tid; i < N_AG; i += 512) {
        int ki = kk[i];
        int cnt = 0;
        int base = (t * N_AG + i) * CAP;
        if (ki != 0) {
            int tkey = ki - 65537;
            int lst[CAP];
            for (int j = head[khash(tkey)]; j >= 0; j = nxt[j]) {
                if (kk[j] == tkey) { if (cnt < CAP) lst[cnt] = j; cnt++; }
            }
            if (cnt > CAP) cnt = CAP;
            for (int a = 1; a < cnt; a++) {           // ascending j = ref sum order
                int v = lst[a]; int b = a - 1;
                while (b >= 0 && lst[b] > v) { lst[b + 1] = lst[b]; b--; }
                lst[b + 1] = v;
            }
            for (int a = 0; a < cnt; a++) midx[base + a] = lst[a];
        }
        mcnt[t * N_AG + i] = cnt;
    }
}

// ---------------------------------------------------------------------------
struct KP {
    const float *X, *masks, *h_in, *c_in;
    const float *Win, *bin, *bsoc, *Wih, *Whh, *bih, *bhh, *Wout, *bout;
    const float *Wef;
    const int *mcnt, *midx;
    float *out, *hist;
    int *flag;
};

__global__ __launch_bounds__(512, 2) void k_persist(KP p)
{
    __shared__ __align__(16) short zsh[4096];   // A-frag order: ((kt*4+q)*16+m)*8+jj
    __shared__ __align__(16) short zsl[4096];
    __shared__ float gbuf[16][258];
    __shared__ float cvs[16][64];
    __shared__ float hs[16][68];
    __shared__ float sX[11][16][2];
    __shared__ float sMask[STEPS][16];
    __shared__ int   sCnt[STEPS][16];
    __shared__ int   sMidx[STEPS][16][CAP];
    __shared__ float sWef[4096];
    __shared__ float sWin[256], sBin[128], sBc[256], sBsoc[64], sWout[128], sBout[2];
    __shared__ float olocal[2][16][2];

    const int tid   = threadIdx.x;
    const int bx    = blockIdx.x;
    const int wbase = bx * 16;
    const int wv    = tid >> 6, lane = tid & 63;
    const int mA    = lane & 15, quad = lane >> 4;
    const int nt0   = 2 * wv;

    // =================== prologue ===================
    if (tid < 256) { sWin[tid] = p.Win[tid]; sBc[tid] = p.bih[tid] + p.bhh[tid]; }
    if (tid < 128) { sBin[tid] = p.bin[tid]; sWout[tid] = p.Wout[tid]; }
    if (tid < 64)  sBsoc[tid] = p.bsoc[tid];
    if (tid < 2)   sBout[tid] = p.bout[tid];
    if (tid < 352) { int tt = tid / 32, r = tid % 32;
                     sX[tt][r >> 1][r & 1] = p.X[tt * (N_AG * 2) + (wbase + (r >> 1)) * 2 + (r & 1)]; }
    if (tid < 320) { int tt = tid / 16, m2 = tid % 16;
                     sMask[tt][m2] = p.masks[tt * N_AG + wbase + m2];
                     sCnt[tt][m2]  = p.mcnt[tt * N_AG + wbase + m2]; }
    for (int i = tid; i < 4096; i += 512) sWef[i] = p.Wef[i];
    for (int i = tid; i < STEPS * 16 * CAP; i += 512) {
        int tt = i / (16 * CAP), r = i % (16 * CAP), m2 = r / CAP, n = r % CAP;
        sMidx[tt][m2][n] = p.midx[(tt * N_AG + wbase + m2) * CAP + n];
    }

    // own h (LDS) + c (registers)
    float c0, c1;
    {
        int m0 = tid >> 6, h0i = tid & 63, m1 = m0 + 8;
        hs[m0][h0i] = p.h_in[(wbase + m0) * 64 + h0i];
        hs[m1][h0i] = p.h_in[(wbase + m1) * 64 + h0i];
        c0 = p.c_in[(wbase + m0) * 64 + h0i];
        c1 = p.c_in[(wbase + m1) * 64 + h0i];
    }

    // register-resident W fragments (hi/lo split), loaded once
    FU wh[2][8], wl[2][8];
    #pragma unroll
    for (int e = 0; e < 2; e++) {
        int g = (nt0 + e) * 16 + mA;
        #pragma unroll
        for (int kt = 0; kt < 8; kt++) {
            int k0 = kt * 32 + quad * 8;        // 8-run never crosses the 192 boundary
            const float* src = (k0 < 192) ? (p.Wih + g * 192 + k0)
                                          : (p.Whh + g * 64 + (k0 - 192));
            unsigned uh[4], ul[4];
            #pragma unroll
            for (int w = 0; w < 4; w++) {
                float a = src[2 * w], b = src[2 * w + 1];
                unsigned short ha = bf16rne(a), hb = bf16rne(b);
                float fa = __uint_as_float(((unsigned)ha) << 16);
                float fb = __uint_as_float(((unsigned)hb) << 16);
                unsigned short la = bf16rne(a - fa), lb = bf16rne(b - fb);
                uh[w] = (unsigned)ha | ((unsigned)hb << 16);
                ul[w] = (unsigned)la | ((unsigned)lb << 16);
            }
            wh[e][kt].q = make_uint4(uh[0], uh[1], uh[2], uh[3]);
            wl[e][kt].q = make_uint4(ul[0], ul[1], ul[2], ul[3]);
        }
    }
    __syncthreads();

    // =================== recurrence (no grid syncs) ===================
    #pragma unroll 1
    for (int t = 0; t < STEPS; t++) {
        // ---- phase A: social cell gather (32 thr/agent; ~12% of agents) ----
        {
            int m = tid >> 5, j = tid & 31;
            int cnt = sCnt[t][m];
            if (cnt > 0) {
                float a0 = 0.f, a1 = 0.f;
                if (t == 0) {
                    for (int n = 0; n < cnt; n++) {
                        int r = sMidx[0][m][n];
                        a0 += p.h_in[r * 64 + j];
                        a1 += p.h_in[r * 64 + j + 32];
                    }
                } else {
                    const float* hb = p.hist + (t - 1) * (N_AG * 64);
                    const int* fl = p.flag + (t - 1) * 128;
                    for (int n = 0; n < cnt; n++) {
                        int r = sMidx[t][m][n];
                        int pb = r >> 4;
                        while (__hip_atomic_load(&fl[pb], __ATOMIC_RELAXED,
                                                 __HIP_MEMORY_SCOPE_AGENT) != t) { }
                        a0 += __hip_atomic_load(&hb[r * 64 + j], __ATOMIC_RELAXED,
                                                __HIP_MEMORY_SCOPE_AGENT);
                        a1 += __hip_atomic_load(&hb[r * 64 + j + 32], __ATOMIC_RELAXED,
                                                __HIP_MEMORY_SCOPE_AGENT);
                    }
                }
                cvs[m][j] = a0; cvs[m][j + 32] = a1;
            }
        }
        __syncthreads();

        // ---- phase B: z-build -> bf16 hi/lo planes in A-frag order ----
        {
            int m = tid >> 5, s5 = tid & 31;
            float px, py;
            if (t <= 10) { px = sX[t][m][0];         py = sX[t][m][1]; }
            else         { px = olocal[t & 1][m][0]; py = olocal[t & 1][m][1]; }
            int cnt = sCnt[t][m];
            int q8 = s5 >> 3, jj = s5 & 7;
            #pragma unroll
            for (int uu = 0; uu < 8; uu++) {
                int c = 32 * uu + s5;
                float v;
                if (uu < 4) {
                    v = fmaxf(sWin[2 * c] * px + sWin[2 * c + 1] * py + sBin[c], 0.f);
                } else if (uu < 6) {
                    int s = c - 128;
                    float acc = sBsoc[s];
                    if (cnt > 0) {                    // cnt>0 implies mask==1
                        const float* wp = &sWef[s * 64];
                        #pragma unroll 4
                        for (int k = 0; k < 64; k += 4) {
                            float4 c4 = *(const float4*)&cvs[m][k];
                            float4 w4 = *(const float4*)&wp[k];
                            acc += c4.x * w4.x + c4.y * w4.y + c4.z * w4.z + c4.w * w4.w;
                        }
                    }
                    v = fmaxf(acc, 0.f);
                } else {
                    v = hs[m][c - 192];
                }
                unsigned short h = bf16rne(v);
                float fh = __uint_as_float(((unsigned)h) << 16);
                unsigned short l = bf16rne(v - fh);
                int fi = ((uu * 4 + q8) * 16 + m) * 8 + jj;
                zsh[fi] = (short)h;
                zsl[fi] = (short)l;
            }
        }
        __syncthreads();

        // ---- phase C: GEMM with register-resident W ----
        {
            const uint4* zhp = (const uint4*)zsh;
            const uint4* zlp = (const uint4*)zsl;
            f32x4 a0v = {0.f, 0.f, 0.f, 0.f};
            f32x4 a1v = {0.f, 0.f, 0.f, 0.f};
            #pragma unroll
            for (int kt = 0; kt < 8; kt++) {
                int fi = (kt * 4 + quad) * 16 + mA;
                FU az, bz;
                az.q = zhp[fi];
                bz.q = zlp[fi];
                a0v = __builtin_amdgcn_mfma_f32_16x16x32_bf16(az.v, wh[0][kt].v, a0v, 0, 0, 0);
                a1v = __builtin_amdgcn_mfma_f32_16x16x32_bf16(az.v, wh[1][kt].v, a1v, 0, 0, 0);
                a0v = __builtin_amdgcn_mfma_f32_16x16x32_bf16(bz.v, wh[0][kt].v, a0v, 0, 0, 0);
                a1v = __builtin_amdgcn_mfma_f32_16x16x32_bf16(bz.v, wh[1][kt].v, a1v, 0, 0, 0);
                a0v = __builtin_amdgcn_mfma_f32_16x16x32_bf16(az.v, wl[0][kt].v, a0v, 0, 0, 0);
                a1v = __builtin_amdgcn_mfma_f32_16x16x32_bf16(az.v, wl[1][kt].v, a1v, 0, 0, 0);
            }
            #pragma unroll
            for (int r = 0; r < 4; r++) {
                int row = quad * 4 + r;           // agent slot
                gbuf[row][nt0 * 16 + mA]       = a0v[r];
                gbuf[row][(nt0 + 1) * 16 + mA] = a1v[r];
            }
        }
        __syncthreads();

        // ---- phase D: LSTM elementwise; c in regs; publish h to hist[t] ----
        {
            float* hpub = p.hist + t * (N_AG * 64);
            int m0 = tid >> 6, hid = tid & 63;
            {
                float gi = gbuf[m0][hid]       + sBc[hid];
                float gf = gbuf[m0][64 + hid]  + sBc[64 + hid];
                float gR = gbuf[m0][128 + hid] + sBc[128 + hid];
                float go = gbuf[m0][192 + hid] + sBc[192 + hid];
                float si = 1.f / (1.f + expf(-gi));
                float sf = 1.f / (1.f + expf(-gf));
                float so = 1.f / (1.f + expf(-go));
                float cn = sf * c0 + si * tanhf(gR);
                float hn = so * tanhf(cn);
                c0 = cn;
                hs[m0][hid] = hn;
                __hip_atomic_store(&hpub[(wbase + m0) * 64 + hid], hn,
                                   __ATOMIC_RELAXED, __HIP_MEMORY_SCOPE_AGENT);
            }
            int m1 = m0 + 8;
            {
                float gi = gbuf[m1][hid]       + sBc[hid];
                float gf = gbuf[m1][64 + hid]  + sBc[64 + hid];
                float gR = gbuf[m1][128 + hid] + sBc[128 + hid];
                float go = gbuf[m1][192 + hid] + sBc[192 + hid];
                float si = 1.f / (1.f + expf(-gi));
                float sf = 1.f / (1.f + expf(-gf));
                float so = 1.f / (1.f + expf(-go));
                float cn = sf * c1 + si * tanhf(gR);
                float hn = so * tanhf(cn);
                c1 = cn;
                hs[m1][hid] = hn;
                __hip_atomic_store(&hpub[(wbase + m1) * 64 + hid], hn,
                                   __ATOMIC_RELAXED, __HIP_MEMORY_SCOPE_AGENT);
            }
        }
        __syncthreads();   // drains vmcnt(0) -> all hist stores acked at coherent point

        // flag AFTER the barrier: publishes "hist[t] complete" for this block
        if (tid == 0)
            __hip_atomic_store(&p.flag[t * 128 + bx], t + 1,
                               __ATOMIC_RELAXED, __HIP_MEMORY_SCOPE_AGENT);

        // ---- phase E: out = (h @ W_out.T + b_out) * mask ----
        if (tid < 32) {
            int m = tid >> 1, d = tid & 1;
            float acc = sBout[d];
            #pragma unroll 4
            for (int k = 0; k < 64; k += 4) {
                float4 h4 = *(const float4*)&hs[m][k];
                float4 w4 = *(const float4*)&sWout[d * 64 + k];
                acc += h4.x * w4.x + h4.y * w4.y + h4.z * w4.z + h4.w * w4.w;
            }
            float val = acc * sMask[t][m];
            p.out[(t * N_AG + wbase + m) * 2 + d] = val;
            olocal[t & 1][m][d] = val;
        }
        __syncthreads();   // olocal stable before next step's phase B
    }
}

// ---------------------------------------------------------------------------
extern "C" void kernel_launch(void* const* d_in, const int* in_sizes, int n_in,
                              void* d_out, int out_size, void* d_ws, size_t ws_size,
                              hipStream_t stream)
{
    KP kp;
    kp.X     = (const float*)d_in[0];
    kp.masks = (const float*)d_in[1];
    kp.h_in  = (const float*)d_in[2];
    kp.c_in  = (const float*)d_in[3];
    // d_in[4] = Y (unused), d_in[5] = T_obs (=9), d_in[6] = T_pred (=19)
    kp.Win   = (const float*)d_in[7];
    kp.bin   = (const float*)d_in[8];
    const float* Wsoc = (const float*)d_in[9];
    kp.bsoc  = (const float*)d_in[10];
    kp.Wih   = (const float*)d_in[11];
    kp.Whh   = (const float*)d_in[12];
    kp.bih   = (const float*)d_in[13];
    kp.bhh   = (const float*)d_in[14];
    kp.Wout  = (const float*)d_in[15];
    kp.bout  = (const float*)d_in[16];
    kp.out   = (float*)d_out;

    float* ws = (float*)d_ws;
    float* hist = ws;                              // 20*2048*64 = 2,621,440
    float* Wef  = hist + STEPS * N_AG * 64;        // 4096
    int*   flag = (int*)(Wef + 4096);              // 20*128
    int*   mcnt = flag + STEPS * 128;              // 20*2048
    int*   midx = mcnt + STEPS * N_AG;             // 20*2048*CAP

    kp.hist = hist; kp.Wef = Wef; kp.flag = flag; kp.mcnt = mcnt; kp.midx = midx;

    k_pre<<<53, 512, 0, stream>>>(kp.X, kp.masks, Wsoc, Wef, mcnt, midx,
                                  kp.out + 20 * N_AG * 2);

    void* args[] = { &kp };
    hipLaunchCooperativeKernel((void*)k_persist, dim3(128), dim3(512), args, 0, stream);
}

// Round 7
// 231.279 us; speedup vs baseline: 3.8181x; 1.1746x over previous
//
#include <hip/hip_runtime.h>
#include <math.h>

// ---------------------------------------------------------------------------
// SocialLstm: T=24, N=2048, INPUT_DIM=2, HIDDEN=64, MEDIATE=128, SOCIAL=64,
// OUT_DIM=2, N_SIZE=2, CELL=0.3, T_obs=9, T_pred=19, WIN=9.
//
// R7 (on R6's 139us k_persist):
//  * tagged 8B (tag<<32|value) publish/poll replaces flag+data two-leg sync;
//    publish only vectors k_pre marked as needed (~12%) -> tiny vmcnt drain.
//  * LDS conflict surgery: sWef/es stride 65 (R6's stride-64 e-dot was a
//    32-way conflict -> 6.67M conflict cycles), padded Win/bin layouts,
//    z-frags written as single ds_write_b128 into 17-slot-padded frag array.
//  * fast sigmoid/tanh via __expf + v_rcp; shuffle-reduce epilogue (4
//    barriers/step).
// MFMA hi/lo bf16 split (ZhWh+ZlWh+ZhWl) verified R3-R6, absmax ~2e-3.
// ---------------------------------------------------------------------------

#define N_AG   2048
#define STEPS  20
#define CAP    12

typedef short short8 __attribute__((ext_vector_type(8)));
typedef float f32x4  __attribute__((ext_vector_type(4)));
union FU { uint4 q; short8 v; };

__device__ __forceinline__ unsigned short bf16rne(float x) {
    unsigned u = __float_as_uint(x);
    unsigned r = (u + 0x7fff + ((u >> 16) & 1)) >> 16;
    return (unsigned short)r;
}

__device__ __forceinline__ int khash(int k) {
    return (int)(((unsigned)k * 2654435761u) >> 21);   // 11-bit bucket
}

__device__ __forceinline__ float fsigm(float x) {
    return __builtin_amdgcn_rcpf(1.f + __expf(-x));
}
__device__ __forceinline__ float ftanh(float x) {
    float e = __expf(2.f * x);
    return 1.f - 2.f * __builtin_amdgcn_rcpf(e + 1.f);
}

// ---------------------------------------------------------------------------
// k_pre: blocks 0..19 = per-step hash match (+ mark need[t-1][j] for every
// matched j); block 20 = We fold; blocks 21..52 = zero out tail frames.
// ---------------------------------------------------------------------------
__global__ __launch_bounds__(512) void k_pre(
    const float* __restrict__ X, const float* __restrict__ masks,
    const float* __restrict__ Wsoc,
    float* __restrict__ Wef, int* __restrict__ mcnt, int* __restrict__ midx,
    int* __restrict__ need, float* __restrict__ otail)
{
    const int bx = blockIdx.x, tid = threadIdx.x;

    if (bx >= 21) {                 // tail zero: 32 blocks x 512 = 16384
        otail[(bx - 21) * 512 + tid] = 0.f;
        return;
    }
    if (bx == 20) {                 // We fold: We[s][k] = sum_w Wsoc[s][w*64+k]
        for (int i = tid; i < 4096; i += 512) {
            int s = i >> 6, k = i & 63;
            float a = 0.f;
            #pragma unroll
            for (int w = 0; w < 9; w++) a += Wsoc[s * 576 + w * 64 + k];
            Wef[i] = a;
        }
        return;
    }

    // hash match for step t = bx
    __shared__ int kk[N_AG];
    __shared__ int head[N_AG];
    __shared__ int nxt[N_AG];
    __shared__ float red[512];
    const int t = bx;
    const float* Xt = X + t * N_AG * 2;

    float mnx = 1e30f, mny = 1e30f;
    for (int i = tid; i < N_AG; i += 512) {
        mnx = fminf(mnx, Xt[2 * i]);
        mny = fminf(mny, Xt[2 * i + 1]);
    }
    red[tid] = mnx; __syncthreads();
    for (int s = 256; s > 0; s >>= 1) { if (tid < s) red[tid] = fminf(red[tid], red[tid + s]); __syncthreads(); }
    float ltx = red[0]; __syncthreads();
    red[tid] = mny; __syncthreads();
    for (int s = 256; s > 0; s >>= 1) { if (tid < s) red[tid] = fminf(red[tid], red[tid + s]); __syncthreads(); }
    float lty = red[0]; __syncthreads();
    ltx -= 1.2f;   // margin = 2*N_SIZE*CELL
    lty -= 1.2f;

    for (int i = tid; i < N_AG; i += 512) {
        float m = masks[t * N_AG + i];
        int px = (int)floorf((Xt[2 * i]     - ltx) / 0.3f);
        int py = (int)floorf((Xt[2 * i + 1] - lty) / 0.3f);
        int im = (int)m;
        px *= im; py *= im;
        kk[i] = px * 65536 + py;    // masked -> 0; real agents have px,py >= 4
        head[i] = -1;
        if (t >= 1) need[(t - 1) * N_AG + i] = 0;
    }
    __syncthreads();
    for (int j = tid; j < N_AG; j += 512) {
        int kj = kk[j];
        if (kj != 0) nxt[j] = atomicExch(&head[khash(kj)], j);
    }
    __syncthreads();
    for (int i = tid; i < N_AG; i += 512) {
        int ki = kk[i];
        int cnt = 0;
        int base = (t * N_AG + i) * CAP;
        if (ki != 0) {
            int tkey = ki - 65537;
            int lst[CAP];
            for (int j = head[khash(tkey)]; j >= 0; j = nxt[j]) {
                if (kk[j] == tkey) { if (cnt < CAP) lst[cnt] = j; cnt++; }
            }
            if (cnt > CAP) cnt = CAP;
            for (int a = 1; a < cnt; a++) {           // ascending j = ref sum order
                int v = lst[a]; int b = a - 1;
                while (b >= 0 && lst[b] > v) { lst[b + 1] = lst[b]; b--; }
                lst[b + 1] = v;
            }
            for (int a = 0; a < cnt; a++) {
                midx[base + a] = lst[a];
                if (t >= 1) need[(t - 1) * N_AG + lst[a]] = 1;   // h_{t-1}[j] needed
            }
        }
        mcnt[t * N_AG + i] = cnt;
    }
}

// ---------------------------------------------------------------------------
struct KP {
    const float *X, *masks, *h_in, *c_in;
    const float *Win, *bin, *bsoc, *Wih, *Whh, *bih, *bhh, *Wout, *bout;
    const float *Wef;
    const int *mcnt, *midx, *need;
    float *out;
    unsigned long long *hist;    // 19 slices x [2048][64] of (tag<<32|f32bits)
};

__global__ __launch_bounds__(512, 2) void k_persist(KP p)
{
    __shared__ __align__(16) uint4 zshq[544];     // frag slot (kt*4+q)*17 + m
    __shared__ __align__(16) uint4 zslq[544];
    __shared__ float gbuf[16][258];
    __shared__ float cvs[16][64];
    __shared__ float es[16][65];
    __shared__ float hs[16][68];
    __shared__ float sWefP[64 * 65];
    __shared__ float2 sWinP[16 * 17];
    __shared__ float sBinP[16 * 9];
    __shared__ float sX[11][16][2];
    __shared__ float sMask[STEPS][16];
    __shared__ int   sCnt[STEPS][16];
    __shared__ int   sNeed[19][16];
    __shared__ int   sMidx[STEPS][16][CAP];
    __shared__ float sBsoc[64], sE0[64], sBc[256], sWout[128], sBout[2];
    __shared__ float olocal[2][16][2];

    const int tid   = threadIdx.x;
    const int bx    = blockIdx.x;
    const int wbase = bx * 16;
    const int wv    = tid >> 6, lane = tid & 63;
    const int mA    = lane & 15, quad = lane >> 4;
    const int nt0   = 2 * wv;

    // =================== prologue ===================
    if (tid < 256) sBc[tid] = p.bih[tid] + p.bhh[tid];
    if (tid < 128) {
        sWout[tid] = p.Wout[tid];
        int c = tid;
        sWinP[(c >> 3) * 17 + (c & 7)] = make_float2(p.Win[2 * c], p.Win[2 * c + 1]);
        sBinP[(c >> 3) * 9 + (c & 7)] = p.bin[c];
    }
    if (tid < 64) { sBsoc[tid] = p.bsoc[tid]; sE0[tid] = fmaxf(p.bsoc[tid], 0.f); }
    if (tid < 2)   sBout[tid] = p.bout[tid];
    if (tid < 352) { int tt = tid / 32, r = tid % 32;
                     sX[tt][r >> 1][r & 1] = p.X[tt * (N_AG * 2) + (wbase + (r >> 1)) * 2 + (r & 1)]; }
    if (tid < 320) { int tt = tid / 16, m2 = tid % 16;
                     sMask[tt][m2] = p.masks[tt * N_AG + wbase + m2];
                     sCnt[tt][m2]  = p.mcnt[tt * N_AG + wbase + m2]; }
    if (tid < 304) { int s = tid / 16, m2 = tid % 16;
                     sNeed[s][m2] = p.need[s * N_AG + wbase + m2]; }
    for (int i = tid; i < 4096; i += 512) sWefP[(i >> 6) * 65 + (i & 63)] = p.Wef[i];
    for (int i = tid; i < STEPS * 16 * CAP; i += 512) {
        int tt = i / (16 * CAP), r = i % (16 * CAP), m2 = r / CAP, n = r % CAP;
        sMidx[tt][m2][n] = p.midx[(tt * N_AG + wbase + m2) * CAP + n];
    }

    // own h (LDS) + c (registers)
    float c0, c1;
    {
        int m0 = tid >> 6, h0i = tid & 63, m1 = m0 + 8;
        hs[m0][h0i] = p.h_in[(wbase + m0) * 64 + h0i];
        hs[m1][h0i] = p.h_in[(wbase + m1) * 64 + h0i];
        c0 = p.c_in[(wbase + m0) * 64 + h0i];
        c1 = p.c_in[(wbase + m1) * 64 + h0i];
    }

    // register-resident W fragments (hi/lo split), loaded once
    FU wh[2][8], wl[2][8];
    #pragma unroll
    for (int e = 0; e < 2; e++) {
        int g = (nt0 + e) * 16 + mA;
        #pragma unroll
        for (int kt = 0; kt < 8; kt++) {
            int k0 = kt * 32 + quad * 8;        // 8-run never crosses the 192 boundary
            const float* src = (k0 < 192) ? (p.Wih + g * 192 + k0)
                                          : (p.Whh + g * 64 + (k0 - 192));
            unsigned uh[4], ul[4];
            #pragma unroll
            for (int w = 0; w < 4; w++) {
                float a = src[2 * w], b = src[2 * w + 1];
                unsigned short ha = bf16rne(a), hb = bf16rne(b);
                float fa = __uint_as_float(((unsigned)ha) << 16);
                float fb = __uint_as_float(((unsigned)hb) << 16);
                unsigned short la = bf16rne(a - fa), lb = bf16rne(b - fb);
                uh[w] = (unsigned)ha | ((unsigned)hb << 16);
                ul[w] = (unsigned)la | ((unsigned)lb << 16);
            }
            wh[e][kt].q = make_uint4(uh[0], uh[1], uh[2], uh[3]);
            wl[e][kt].q = make_uint4(ul[0], ul[1], ul[2], ul[3]);
        }
    }
    __syncthreads();

    // =================== recurrence ===================
    #pragma unroll 1
    for (int t = 0; t < STEPS; t++) {
        // ---- phase A: gather cvs via tagged polls, then e in-wave ----
        {
            int m = tid >> 5, j = tid & 31;
            int cnt = sCnt[t][m];
            if (cnt > 0) {
                float a0 = 0.f, a1 = 0.f;
                if (t == 0) {
                    for (int n = 0; n < cnt; n++) {
                        int r = sMidx[0][m][n];
                        a0 += p.h_in[r * 64 + j];
                        a1 += p.h_in[r * 64 + j + 32];
                    }
                } else {
                    const unsigned long long* hb = p.hist + (size_t)(t - 1) * (N_AG * 64);
                    const unsigned tagw = (unsigned)t;
                    for (int n = 0; n < cnt; n++) {
                        int r = sMidx[t][m][n];
                        unsigned long long w0, w1;
                        do { w0 = __hip_atomic_load(&hb[r * 64 + j], __ATOMIC_RELAXED,
                                                    __HIP_MEMORY_SCOPE_AGENT);
                        } while ((unsigned)(w0 >> 32) != tagw);
                        do { w1 = __hip_atomic_load(&hb[r * 64 + j + 32], __ATOMIC_RELAXED,
                                                    __HIP_MEMORY_SCOPE_AGENT);
                        } while ((unsigned)(w1 >> 32) != tagw);
                        a0 += __uint_as_float((unsigned)w0);
                        a1 += __uint_as_float((unsigned)w1);
                    }
                }
                cvs[m][j] = a0; cvs[m][j + 32] = a1;
                // e = relu(cvs . WefP + bsoc)  (same 32 lanes wrote cvs[m];
                // in-wave LDS FIFO ordering makes this safe without a barrier)
                float acc0 = sBsoc[j], acc1 = sBsoc[j + 32];
                const float* w0p = &sWefP[j * 65];
                const float* w1p = &sWefP[(j + 32) * 65];
                for (int k = 0; k < 64; k++) {
                    float cv = cvs[m][k];
                    acc0 += cv * w0p[k];
                    acc1 += cv * w1p[k];
                }
                es[m][j]      = fmaxf(acc0, 0.f);
                es[m][j + 32] = fmaxf(acc1, 0.f);
            } else {
                es[m][j]      = sE0[j];
                es[m][j + 32] = sE0[j + 32];
            }
        }
        __syncthreads();

        // ---- phase B: 8 consecutive z-cols per thread -> one b128/plane ----
        {
            int m = tid >> 5, s5 = tid & 31;
            float v[8];
            if (s5 < 16) {                       // r-cols c = s5*8 + j
                float px, py;
                if (t <= 10) { px = sX[t][m][0];         py = sX[t][m][1]; }
                else         { px = olocal[t & 1][m][0]; py = olocal[t & 1][m][1]; }
                #pragma unroll
                for (int j = 0; j < 8; j++) {
                    float2 w2 = sWinP[s5 * 17 + j];
                    v[j] = fmaxf(w2.x * px + w2.y * py + sBinP[s5 * 9 + j], 0.f);
                }
            } else if (s5 < 24) {                // e-cols
                #pragma unroll
                for (int j = 0; j < 8; j++) v[j] = es[m][(s5 - 16) * 8 + j];
            } else {                             // h-cols
                #pragma unroll
                for (int j = 0; j < 8; j++) v[j] = hs[m][(s5 - 24) * 8 + j];
            }
            unsigned uh[4], ul[4];
            #pragma unroll
            for (int w = 0; w < 4; w++) {
                float v0 = v[2 * w], v1 = v[2 * w + 1];
                unsigned short h0 = bf16rne(v0), h1 = bf16rne(v1);
                float f0 = __uint_as_float(((unsigned)h0) << 16);
                float f1 = __uint_as_float(((unsigned)h1) << 16);
                unsigned short l0 = bf16rne(v0 - f0), l1 = bf16rne(v1 - f1);
                uh[w] = (unsigned)h0 | ((unsigned)h1 << 16);
                ul[w] = (unsigned)l0 | ((unsigned)l1 << 16);
            }
            zshq[s5 * 17 + m] = make_uint4(uh[0], uh[1], uh[2], uh[3]);
            zslq[s5 * 17 + m] = make_uint4(ul[0], ul[1], ul[2], ul[3]);
        }
        __syncthreads();

        // ---- phase C: GEMM with register-resident W ----
        {
            f32x4 a0v = {0.f, 0.f, 0.f, 0.f};
            f32x4 a1v = {0.f, 0.f, 0.f, 0.f};
            #pragma unroll
            for (int kt = 0; kt < 8; kt++) {
                int fi = (kt * 4 + quad) * 17 + mA;
                FU az, bz;
                az.q = zshq[fi];
                bz.q = zslq[fi];
                a0v = __builtin_amdgcn_mfma_f32_16x16x32_bf16(az.v, wh[0][kt].v, a0v, 0, 0, 0);
                a1v = __builtin_amdgcn_mfma_f32_16x16x32_bf16(az.v, wh[1][kt].v, a1v, 0, 0, 0);
                a0v = __builtin_amdgcn_mfma_f32_16x16x32_bf16(bz.v, wh[0][kt].v, a0v, 0, 0, 0);
                a1v = __builtin_amdgcn_mfma_f32_16x16x32_bf16(bz.v, wh[1][kt].v, a1v, 0, 0, 0);
                a0v = __builtin_amdgcn_mfma_f32_16x16x32_bf16(az.v, wl[0][kt].v, a0v, 0, 0, 0);
                a1v = __builtin_amdgcn_mfma_f32_16x16x32_bf16(az.v, wl[1][kt].v, a1v, 0, 0, 0);
            }
            #pragma unroll
            for (int r = 0; r < 4; r++) {
                int row = quad * 4 + r;           // agent slot
                gbuf[row][nt0 * 16 + mA]       = a0v[r];
                gbuf[row][(nt0 + 1) * 16 + mA] = a1v[r];
            }
        }
        __syncthreads();

        // ---- phase D: LSTM; tagged publish of needed h; E: out reduce ----
        {
            int m0 = tid >> 6, hid = tid & 63, m1 = m0 + 8;
            float hn0, hn1;
            {
                float gi = gbuf[m0][hid]       + sBc[hid];
                float gf = gbuf[m0][64 + hid]  + sBc[64 + hid];
                float gR = gbuf[m0][128 + hid] + sBc[128 + hid];
                float go = gbuf[m0][192 + hid] + sBc[192 + hid];
                float cn = fsigm(gf) * c0 + fsigm(gi) * ftanh(gR);
                hn0 = fsigm(go) * ftanh(cn);
                c0 = cn;
                hs[m0][hid] = hn0;
            }
            {
                float gi = gbuf[m1][hid]       + sBc[hid];
                float gf = gbuf[m1][64 + hid]  + sBc[64 + hid];
                float gR = gbuf[m1][128 + hid] + sBc[128 + hid];
                float go = gbuf[m1][192 + hid] + sBc[192 + hid];
                float cn = fsigm(gf) * c1 + fsigm(gi) * ftanh(gR);
                hn1 = fsigm(go) * ftanh(cn);
                c1 = cn;
                hs[m1][hid] = hn1;
            }
            if (t <= 18) {
                unsigned long long* hp = p.hist + (size_t)t * (N_AG * 64);
                unsigned long long tg = ((unsigned long long)(t + 1)) << 32;
                if (sNeed[t][m0])
                    __hip_atomic_store(&hp[(wbase + m0) * 64 + hid],
                                       tg | (unsigned long long)__float_as_uint(hn0),
                                       __ATOMIC_RELAXED, __HIP_MEMORY_SCOPE_AGENT);
                if (sNeed[t][m1])
                    __hip_atomic_store(&hp[(wbase + m1) * 64 + hid],
                                       tg | (unsigned long long)__float_as_uint(hn1),
                                       __ATOMIC_RELAXED, __HIP_MEMORY_SCOPE_AGENT);
            }

            // phase E: wave-shuffle reduction for out (agents m0, m1)
            float w0 = sWout[hid], w1 = sWout[64 + hid];
            float p00 = hn0 * w0, p01 = hn0 * w1;
            float p10 = hn1 * w0, p11 = hn1 * w1;
            #pragma unroll
            for (int off = 32; off >= 1; off >>= 1) {
                p00 += __shfl_xor(p00, off);
                p01 += __shfl_xor(p01, off);
                p10 += __shfl_xor(p10, off);
                p11 += __shfl_xor(p11, off);
            }
            if (hid == 0) {
                float mk0 = sMask[t][m0], mk1 = sMask[t][m1];
                float o00 = (p00 + sBout[0]) * mk0, o01 = (p01 + sBout[1]) * mk0;
                float o10 = (p10 + sBout[0]) * mk1, o11 = (p11 + sBout[1]) * mk1;
                p.out[(t * N_AG + wbase + m0) * 2 + 0] = o00;
                p.out[(t * N_AG + wbase + m0) * 2 + 1] = o01;
                p.out[(t * N_AG + wbase + m1) * 2 + 0] = o10;
                p.out[(t * N_AG + wbase + m1) * 2 + 1] = o11;
                olocal[t & 1][m0][0] = o00; olocal[t & 1][m0][1] = o01;
                olocal[t & 1][m1][0] = o10; olocal[t & 1][m1][1] = o11;
            }
        }
        __syncthreads();   // hs + olocal stable before next step
    }
}

// ---------------------------------------------------------------------------
extern "C" void kernel_launch(void* const* d_in, const int* in_sizes, int n_in,
                              void* d_out, int out_size, void* d_ws, size_t ws_size,
                              hipStream_t stream)
{
    KP kp;
    kp.X     = (const float*)d_in[0];
    kp.masks = (const float*)d_in[1];
    kp.h_in  = (const float*)d_in[2];
    kp.c_in  = (const float*)d_in[3];
    // d_in[4] = Y (unused), d_in[5] = T_obs (=9), d_in[6] = T_pred (=19)
    kp.Win   = (const float*)d_in[7];
    kp.bin   = (const float*)d_in[8];
    const float* Wsoc = (const float*)d_in[9];
    kp.bsoc  = (const float*)d_in[10];
    kp.Wih   = (const float*)d_in[11];
    kp.Whh   = (const float*)d_in[12];
    kp.bih   = (const float*)d_in[13];
    kp.bhh   = (const float*)d_in[14];
    kp.Wout  = (const float*)d_in[15];
    kp.bout  = (const float*)d_in[16];
    kp.out   = (float*)d_out;

    unsigned long long* hist = (unsigned long long*)d_ws;   // 19*2048*64 (8B each)
    float* Wef = (float*)(hist + 19 * N_AG * 64);           // 4096
    int*   need = (int*)(Wef + 4096);                       // 19*2048
    int*   mcnt = need + 19 * N_AG;                         // 20*2048
    int*   midx = mcnt + STEPS * N_AG;                      // 20*2048*CAP

    kp.hist = hist; kp.Wef = Wef; kp.need = need; kp.mcnt = mcnt; kp.midx = midx;

    k_pre<<<53, 512, 0, stream>>>(kp.X, kp.masks, Wsoc, Wef, mcnt, midx, need,
                                  kp.out + 20 * N_AG * 2);

    void* args[] = { &kp };
    hipLaunchCooperativeKernel((void*)k_persist, dim3(128), dim3(512), args, 0, stream);
}

// Round 8
// 195.061 us; speedup vs baseline: 4.5271x; 1.1857x over previous
//
#include <hip/hip_runtime.h>
#include <math.h>

// ---------------------------------------------------------------------------
// SocialLstm: T=24, N=2048, INPUT_DIM=2, HIDDEN=64, MEDIATE=128, SOCIAL=64,
// OUT_DIM=2, N_SIZE=2, CELL=0.3, T_obs=9, T_pred=19, WIN=9.
//
// R8 (on R7's 105us k_persist / 231 total):
//  * regular launch (no grid.sync since R6 -> cooperative API was pure
//    drain overhead; 128 blocks x ~84KB LDS = 1 block/CU, all co-resident).
//  * poll moved off the step head: B1 builds r/h frags, then matched
//    half-waves poll+e-dot+shuffle-transpose to e-frags IN REGISTERS while
//    other waves run the 36 r/h-tile MFMAs (C1). kt 4,5 (e-tiles) run after
//    the bar (C2). Still 4 barriers/step. Combined 2-address poll.
//  * unmatched agents' e-frag = const relu(bsoc) frag, prebuilt once.
// MFMA hi/lo bf16 split (ZhWh+ZlWh+ZhWl) verified R3-R7, absmax ~2e-3.
// ---------------------------------------------------------------------------

#define N_AG   2048
#define STEPS  20
#define CAP    12

typedef short short8 __attribute__((ext_vector_type(8)));
typedef float f32x4  __attribute__((ext_vector_type(4)));
union FU { uint4 q; short8 v; };

__device__ __forceinline__ unsigned short bf16rne(float x) {
    unsigned u = __float_as_uint(x);
    unsigned r = (u + 0x7fff + ((u >> 16) & 1)) >> 16;
    return (unsigned short)r;
}

__device__ __forceinline__ int khash(int k) {
    return (int)(((unsigned)k * 2654435761u) >> 21);   // 11-bit bucket
}

__device__ __forceinline__ float fsigm(float x) {
    return __builtin_amdgcn_rcpf(1.f + __expf(-x));
}
__device__ __forceinline__ float ftanh(float x) {
    float e = __expf(2.f * x);
    return 1.f - 2.f * __builtin_amdgcn_rcpf(e + 1.f);
}

// ---------------------------------------------------------------------------
// k_pre: blocks 0..19 = per-step hash match (+ mark need[t-1][j] for every
// matched j); block 20 = We fold; blocks 21..52 = zero out tail frames.
// ---------------------------------------------------------------------------
__global__ __launch_bounds__(512) void k_pre(
    const float* __restrict__ X, const float* __restrict__ masks,
    const float* __restrict__ Wsoc,
    float* __restrict__ Wef, int* __restrict__ mcnt, int* __restrict__ midx,
    int* __restrict__ need, float* __restrict__ otail)
{
    const int bx = blockIdx.x, tid = threadIdx.x;

    if (bx >= 21) {                 // tail zero: 32 blocks x 512 = 16384
        otail[(bx - 21) * 512 + tid] = 0.f;
        return;
    }
    if (bx == 20) {                 // We fold: We[s][k] = sum_w Wsoc[s][w*64+k]
        for (int i = tid; i < 4096; i += 512) {
            int s = i >> 6, k = i & 63;
            float a = 0.f;
            #pragma unroll
            for (int w = 0; w < 9; w++) a += Wsoc[s * 576 + w * 64 + k];
            Wef[i] = a;
        }
        return;
    }

    // hash match for step t = bx
    __shared__ int kk[N_AG];
    __shared__ int head[N_AG];
    __shared__ int nxt[N_AG];
    __shared__ float red[512];
    const int t = bx;
    const float* Xt = X + t * N_AG * 2;

    float mnx = 1e30f, mny = 1e30f;
    for (int i = tid; i < N_AG; i += 512) {
        mnx = fminf(mnx, Xt[2 * i]);
        mny = fminf(mny, Xt[2 * i + 1]);
    }
    red[tid] = mnx; __syncthreads();
    for (int s = 256; s > 0; s >>= 1) { if (tid < s) red[tid] = fminf(red[tid], red[tid + s]); __syncthreads(); }
    float ltx = red[0]; __syncthreads();
    red[tid] = mny; __syncthreads();
    for (int s = 256; s > 0; s >>= 1) { if (tid < s) red[tid] = fminf(red[tid], red[tid + s]); __syncthreads(); }
    float lty = red[0]; __syncthreads();
    ltx -= 1.2f;   // margin = 2*N_SIZE*CELL
    lty -= 1.2f;

    for (int i = tid; i < N_AG; i += 512) {
        float m = masks[t * N_AG + i];
        int px = (int)floorf((Xt[2 * i]     - ltx) / 0.3f);
        int py = (int)floorf((Xt[2 * i + 1] - lty) / 0.3f);
        int im = (int)m;
        px *= im; py *= im;
        kk[i] = px * 65536 + py;    // masked -> 0; real agents have px,py >= 4
        head[i] = -1;
        if (t >= 1) need[(t - 1) * N_AG + i] = 0;
    }
    __syncthreads();
    for (int j = tid; j < N_AG; j += 512) {
        int kj = kk[j];
        if (kj != 0) nxt[j] = atomicExch(&head[khash(kj)], j);
    }
    __syncthreads();
    for (int i = tid; i < N_AG; i += 512) {
        int ki = kk[i];
        int cnt = 0;
        int base = (t * N_AG + i) * CAP;
        if (ki != 0) {
            int tkey = ki - 65537;
            int lst[CAP];
            for (int j = head[khash(tkey)]; j >= 0; j = nxt[j]) {
                if (kk[j] == tkey) { if (cnt < CAP) lst[cnt] = j; cnt++; }
            }
            if (cnt > CAP) cnt = CAP;
            for (int a = 1; a < cnt; a++) {           // ascending j = ref sum order
                int v = lst[a]; int b = a - 1;
                while (b >= 0 && lst[b] > v) { lst[b + 1] = lst[b]; b--; }
                lst[b + 1] = v;
            }
            for (int a = 0; a < cnt; a++) {
                midx[base + a] = lst[a];
                if (t >= 1) need[(t - 1) * N_AG + lst[a]] = 1;   // h_{t-1}[j] needed
            }
        }
        mcnt[t * N_AG + i] = cnt;
    }
}

// ---------------------------------------------------------------------------
struct KP {
    const float *X, *masks, *h_in, *c_in;
    const float *Win, *bin, *bsoc, *Wih, *Whh, *bih, *bhh, *Wout, *bout;
    const float *Wef;
    const int *mcnt, *midx, *need;
    float *out;
    unsigned long long *hist;    // 19 slices x [2048][64] of (tag<<32|f32bits)
};

__global__ __launch_bounds__(512, 2) void k_persist(KP p)
{
    __shared__ __align__(16) uint4 zshq[544];     // frag slot (kt*4+q)*17 + m
    __shared__ __align__(16) uint4 zslq[544];
    __shared__ float gbuf[16][258];
    __shared__ float cvs[16][64];
    __shared__ float hs[16][68];
    __shared__ float sWefP[64 * 65];
    __shared__ float2 sWinP[16 * 17];
    __shared__ float sBinP[16 * 9];
    __shared__ float sX[11][16][2];
    __shared__ float sMask[STEPS][16];
    __shared__ int   sCnt[STEPS][16];
    __shared__ int   sNeed[19][16];
    __shared__ int   sMidx[STEPS][16][CAP];
    __shared__ float sBsoc[64], sBc[256], sWout[128], sBout[2];
    __shared__ uint4 sE0h[8], sE0l[8];
    __shared__ float olocal[2][16][2];

    const int tid   = threadIdx.x;
    const int bx    = blockIdx.x;
    const int wbase = bx * 16;
    const int wv    = tid >> 6, lane = tid & 63;
    const int mA    = lane & 15, quad = lane >> 4;
    const int nt0   = 2 * wv;

    // =================== prologue ===================
    if (tid < 256) sBc[tid] = p.bih[tid] + p.bhh[tid];
    if (tid < 128) {
        sWout[tid] = p.Wout[tid];
        int c = tid;
        sWinP[(c >> 3) * 17 + (c & 7)] = make_float2(p.Win[2 * c], p.Win[2 * c + 1]);
        sBinP[(c >> 3) * 9 + (c & 7)] = p.bin[c];
    }
    if (tid < 64) sBsoc[tid] = p.bsoc[tid];
    if (tid < 2)  sBout[tid] = p.bout[tid];
    if (tid < 8) {              // const e0-frag (relu(bsoc)) for unmatched agents
        unsigned uh[4], ul[4];
        #pragma unroll
        for (int w = 0; w < 4; w++) {
            float v0 = fmaxf(p.bsoc[tid * 8 + 2 * w], 0.f);
            float v1 = fmaxf(p.bsoc[tid * 8 + 2 * w + 1], 0.f);
            unsigned short h0 = bf16rne(v0), h1 = bf16rne(v1);
            float f0 = __uint_as_float(((unsigned)h0) << 16);
            float f1 = __uint_as_float(((unsigned)h1) << 16);
            unsigned short l0 = bf16rne(v0 - f0), l1 = bf16rne(v1 - f1);
            uh[w] = (unsigned)h0 | ((unsigned)h1 << 16);
            ul[w] = (unsigned)l0 | ((unsigned)l1 << 16);
        }
        sE0h[tid] = make_uint4(uh[0], uh[1], uh[2], uh[3]);
        sE0l[tid] = make_uint4(ul[0], ul[1], ul[2], ul[3]);
    }
    if (tid < 352) { int tt = tid / 32, r = tid % 32;
                     sX[tt][r >> 1][r & 1] = p.X[tt * (N_AG * 2) + (wbase + (r >> 1)) * 2 + (r & 1)]; }
    if (tid < 320) { int tt = tid / 16, m2 = tid % 16;
                     sMask[tt][m2] = p.masks[tt * N_AG + wbase + m2];
                     sCnt[tt][m2]  = p.mcnt[tt * N_AG + wbase + m2]; }
    if (tid < 304) { int s = tid / 16, m2 = tid % 16;
                     sNeed[s][m2] = p.need[s * N_AG + wbase + m2]; }
    for (int i = tid; i < 4096; i += 512) sWefP[(i >> 6) * 65 + (i & 63)] = p.Wef[i];
    for (int i = tid; i < STEPS * 16 * CAP; i += 512) {
        int tt = i / (16 * CAP), r = i % (16 * CAP), m2 = r / CAP, n = r % CAP;
        sMidx[tt][m2][n] = p.midx[(tt * N_AG + wbase + m2) * CAP + n];
    }

    // own h (LDS) + c (registers)
    float c0, c1;
    {
        int m0 = tid >> 6, h0i = tid & 63, m1 = m0 + 8;
        hs[m0][h0i] = p.h_in[(wbase + m0) * 64 + h0i];
        hs[m1][h0i] = p.h_in[(wbase + m1) * 64 + h0i];
        c0 = p.c_in[(wbase + m0) * 64 + h0i];
        c1 = p.c_in[(wbase + m1) * 64 + h0i];
    }

    // register-resident W fragments (hi/lo split), loaded once
    FU wh[2][8], wl[2][8];
    #pragma unroll
    for (int e = 0; e < 2; e++) {
        int g = (nt0 + e) * 16 + mA;
        #pragma unroll
        for (int kt = 0; kt < 8; kt++) {
            int k0 = kt * 32 + quad * 8;        // 8-run never crosses the 192 boundary
            const float* src = (k0 < 192) ? (p.Wih + g * 192 + k0)
                                          : (p.Whh + g * 64 + (k0 - 192));
            unsigned uh[4], ul[4];
            #pragma unroll
            for (int w = 0; w < 4; w++) {
                float a = src[2 * w], b = src[2 * w + 1];
                unsigned short ha = bf16rne(a), hb = bf16rne(b);
                float fa = __uint_as_float(((unsigned)ha) << 16);
                float fb = __uint_as_float(((unsigned)hb) << 16);
                unsigned short la = bf16rne(a - fa), lb = bf16rne(b - fb);
                uh[w] = (unsigned)ha | ((unsigned)hb << 16);
                ul[w] = (unsigned)la | ((unsigned)lb << 16);
            }
            wh[e][kt].q = make_uint4(uh[0], uh[1], uh[2], uh[3]);
            wl[e][kt].q = make_uint4(ul[0], ul[1], ul[2], ul[3]);
        }
    }
    __syncthreads();

    // =================== recurrence ===================
    #pragma unroll 1
    for (int t = 0; t < STEPS; t++) {
        const int m5 = tid >> 5, s5 = tid & 31;
        const int cnt5 = sCnt[t][m5];

        // ---- B1: r-frags, h-frags, const-e-frags for unmatched ----
        {
            if (s5 < 16) {                       // r-cols c = s5*8 + j
                float px, py;
                if (t <= 10) { px = sX[t][m5][0];         py = sX[t][m5][1]; }
                else         { px = olocal[t & 1][m5][0]; py = olocal[t & 1][m5][1]; }
                float v[8];
                #pragma unroll
                for (int j = 0; j < 8; j++) {
                    float2 w2 = sWinP[s5 * 17 + j];
                    v[j] = fmaxf(w2.x * px + w2.y * py + sBinP[s5 * 9 + j], 0.f);
                }
                unsigned uh[4], ul[4];
                #pragma unroll
                for (int w = 0; w < 4; w++) {
                    float v0 = v[2 * w], v1 = v[2 * w + 1];
                    unsigned short h0 = bf16rne(v0), h1 = bf16rne(v1);
                    float f0 = __uint_as_float(((unsigned)h0) << 16);
                    float f1 = __uint_as_float(((unsigned)h1) << 16);
                    unsigned short l0 = bf16rne(v0 - f0), l1 = bf16rne(v1 - f1);
                    uh[w] = (unsigned)h0 | ((unsigned)h1 << 16);
                    ul[w] = (unsigned)l0 | ((unsigned)l1 << 16);
                }
                zshq[s5 * 17 + m5] = make_uint4(uh[0], uh[1], uh[2], uh[3]);
                zslq[s5 * 17 + m5] = make_uint4(ul[0], ul[1], ul[2], ul[3]);
            } else if (s5 < 24) {                // e-cols: const frag if unmatched
                if (cnt5 == 0) {
                    zshq[s5 * 17 + m5] = sE0h[s5 - 16];
                    zslq[s5 * 17 + m5] = sE0l[s5 - 16];
                }
            } else {                             // h-cols
                float v[8];
                #pragma unroll
                for (int j = 0; j < 8; j++) v[j] = hs[m5][(s5 - 24) * 8 + j];
                unsigned uh[4], ul[4];
                #pragma unroll
                for (int w = 0; w < 4; w++) {
                    float v0 = v[2 * w], v1 = v[2 * w + 1];
                    unsigned short h0 = bf16rne(v0), h1 = bf16rne(v1);
                    float f0 = __uint_as_float(((unsigned)h0) << 16);
                    float f1 = __uint_as_float(((unsigned)h1) << 16);
                    unsigned short l0 = bf16rne(v0 - f0), l1 = bf16rne(v1 - f1);
                    uh[w] = (unsigned)h0 | ((unsigned)h1 << 16);
                    ul[w] = (unsigned)l0 | ((unsigned)l1 << 16);
                }
                zshq[s5 * 17 + m5] = make_uint4(uh[0], uh[1], uh[2], uh[3]);
                zslq[s5 * 17 + m5] = make_uint4(ul[0], ul[1], ul[2], ul[3]);
            }
        }
        __syncthreads();   // bar1: r/h/const-e frags visible

        // ---- A'': matched half-waves poll + e-dot + shuffle-frag ----
        if (cnt5 > 0) {
            float a0 = 0.f, a1 = 0.f;
            if (t == 0) {
                for (int n = 0; n < cnt5; n++) {
                    int r = sMidx[0][m5][n];
                    a0 += p.h_in[r * 64 + s5];
                    a1 += p.h_in[r * 64 + s5 + 32];
                }
            } else {
                const unsigned long long* hb = p.hist + (size_t)(t - 1) * (N_AG * 64);
                const unsigned tagw = (unsigned)t;
                for (int n = 0; n < cnt5; n++) {
                    int r = sMidx[t][m5][n];
                    unsigned long long w0, w1;
                    do {
                        w0 = __hip_atomic_load(&hb[r * 64 + s5], __ATOMIC_RELAXED,
                                               __HIP_MEMORY_SCOPE_AGENT);
                        w1 = __hip_atomic_load(&hb[r * 64 + s5 + 32], __ATOMIC_RELAXED,
                                               __HIP_MEMORY_SCOPE_AGENT);
                    } while ((unsigned)(w0 >> 32) != tagw || (unsigned)(w1 >> 32) != tagw);
                    a0 += __uint_as_float((unsigned)w0);
                    a1 += __uint_as_float((unsigned)w1);
                }
            }
            cvs[m5][s5] = a0; cvs[m5][s5 + 32] = a1;
            // e-dot: cols s5 and s5+32 (in-wave cvs read: same half-wave wrote it)
            float acc0 = sBsoc[s5], acc1 = sBsoc[s5 + 32];
            const float* w0p = &sWefP[s5 * 65];
            const float* w1p = &sWefP[(s5 + 32) * 65];
            for (int k = 0; k < 64; k++) {
                float cv = cvs[m5][k];
                acc0 += cv * w0p[k];
                acc1 += cv * w1p[k];
            }
            acc0 = fmaxf(acc0, 0.f);
            acc1 = fmaxf(acc1, 0.f);
            // shuffle-transpose: writer lanes s5<8 gather cols 8*s5..8*s5+7
            const int base = (m5 & 1) * 32;
            float v[8];
            #pragma unroll
            for (int jj = 0; jj < 8; jj++) {
                int c = s5 * 8 + jj;             // meaningful for s5<8
                int srcl = base + ((c < 32 ? c : c - 32) & 31);
                float va = __shfl(acc0, srcl, 64);
                float vb = __shfl(acc1, srcl, 64);
                v[jj] = (c < 32) ? va : vb;
            }
            if (s5 < 8) {
                unsigned uh[4], ul[4];
                #pragma unroll
                for (int w = 0; w < 4; w++) {
                    float v0 = v[2 * w], v1 = v[2 * w + 1];
                    unsigned short h0 = bf16rne(v0), h1 = bf16rne(v1);
                    float f0 = __uint_as_float(((unsigned)h0) << 16);
                    float f1 = __uint_as_float(((unsigned)h1) << 16);
                    unsigned short l0 = bf16rne(v0 - f0), l1 = bf16rne(v1 - f1);
                    uh[w] = (unsigned)h0 | ((unsigned)h1 << 16);
                    ul[w] = (unsigned)l0 | ((unsigned)l1 << 16);
                }
                zshq[(16 + s5) * 17 + m5] = make_uint4(uh[0], uh[1], uh[2], uh[3]);
                zslq[(16 + s5) * 17 + m5] = make_uint4(ul[0], ul[1], ul[2], ul[3]);
            }
        }

        // ---- C1: r/h k-tiles (0..3, 6, 7) — overlaps other waves' polls ----
        f32x4 a0v = {0.f, 0.f, 0.f, 0.f};
        f32x4 a1v = {0.f, 0.f, 0.f, 0.f};
        #pragma unroll
        for (int u = 0; u < 6; u++) {
            const int kt = (u < 4) ? u : u + 2;   // 0,1,2,3,6,7
            int fi = (kt * 4 + quad) * 17 + mA;
            FU az, bz;
            az.q = zshq[fi];
            bz.q = zslq[fi];
            a0v = __builtin_amdgcn_mfma_f32_16x16x32_bf16(az.v, wh[0][kt].v, a0v, 0, 0, 0);
            a1v = __builtin_amdgcn_mfma_f32_16x16x32_bf16(az.v, wh[1][kt].v, a1v, 0, 0, 0);
            a0v = __builtin_amdgcn_mfma_f32_16x16x32_bf16(bz.v, wh[0][kt].v, a0v, 0, 0, 0);
            a1v = __builtin_amdgcn_mfma_f32_16x16x32_bf16(bz.v, wh[1][kt].v, a1v, 0, 0, 0);
            a0v = __builtin_amdgcn_mfma_f32_16x16x32_bf16(az.v, wl[0][kt].v, a0v, 0, 0, 0);
            a1v = __builtin_amdgcn_mfma_f32_16x16x32_bf16(az.v, wl[1][kt].v, a1v, 0, 0, 0);
        }
        __syncthreads();   // bar2: e-frags visible, all C1 issued

        // ---- C2: e k-tiles (4, 5); write gbuf ----
        #pragma unroll
        for (int kt = 4; kt <= 5; kt++) {
            int fi = (kt * 4 + quad) * 17 + mA;
            FU az, bz;
            az.q = zshq[fi];
            bz.q = zslq[fi];
            a0v = __builtin_amdgcn_mfma_f32_16x16x32_bf16(az.v, wh[0][kt].v, a0v, 0, 0, 0);
            a1v = __builtin_amdgcn_mfma_f32_16x16x32_bf16(az.v, wh[1][kt].v, a1v, 0, 0, 0);
            a0v = __builtin_amdgcn_mfma_f32_16x16x32_bf16(bz.v, wh[0][kt].v, a0v, 0, 0, 0);
            a1v = __builtin_amdgcn_mfma_f32_16x16x32_bf16(bz.v, wh[1][kt].v, a1v, 0, 0, 0);
            a0v = __builtin_amdgcn_mfma_f32_16x16x32_bf16(az.v, wl[0][kt].v, a0v, 0, 0, 0);
            a1v = __builtin_amdgcn_mfma_f32_16x16x32_bf16(az.v, wl[1][kt].v, a1v, 0, 0, 0);
        }
        #pragma unroll
        for (int r = 0; r < 4; r++) {
            int row = quad * 4 + r;           // agent slot
            gbuf[row][nt0 * 16 + mA]       = a0v[r];
            gbuf[row][(nt0 + 1) * 16 + mA] = a1v[r];
        }
        __syncthreads();   // bar3: gbuf visible

        // ---- D: LSTM; tagged publish of needed h; E: out reduce ----
        {
            int m0 = tid >> 6, hid = tid & 63, m1 = m0 + 8;
            float hn0, hn1;
            {
                float gi = gbuf[m0][hid]       + sBc[hid];
                float gf = gbuf[m0][64 + hid]  + sBc[64 + hid];
                float gR = gbuf[m0][128 + hid] + sBc[128 + hid];
                float go = gbuf[m0][192 + hid] + sBc[192 + hid];
                float cn = fsigm(gf) * c0 + fsigm(gi) * ftanh(gR);
                hn0 = fsigm(go) * ftanh(cn);
                c0 = cn;
                hs[m0][hid] = hn0;
            }
            {
                float gi = gbuf[m1][hid]       + sBc[hid];
                float gf = gbuf[m1][64 + hid]  + sBc[64 + hid];
                float gR = gbuf[m1][128 + hid] + sBc[128 + hid];
                float go = gbuf[m1][192 + hid] + sBc[192 + hid];
                float cn = fsigm(gf) * c1 + fsigm(gi) * ftanh(gR);
                hn1 = fsigm(go) * ftanh(cn);
                c1 = cn;
                hs[m1][hid] = hn1;
            }
            if (t <= 18) {
                unsigned long long* hp = p.hist + (size_t)t * (N_AG * 64);
                unsigned long long tg = ((unsigned long long)(t + 1)) << 32;
                if (sNeed[t][m0])
                    __hip_atomic_store(&hp[(wbase + m0) * 64 + hid],
                                       tg | (unsigned long long)__float_as_uint(hn0),
                                       __ATOMIC_RELAXED, __HIP_MEMORY_SCOPE_AGENT);
                if (sNeed[t][m1])
                    __hip_atomic_store(&hp[(wbase + m1) * 64 + hid],
                                       tg | (unsigned long long)__float_as_uint(hn1),
                                       __ATOMIC_RELAXED, __HIP_MEMORY_SCOPE_AGENT);
            }

            // E: wave-shuffle reduction for out (agents m0, m1)
            float w0 = sWout[hid], w1 = sWout[64 + hid];
            float p00 = hn0 * w0, p01 = hn0 * w1;
            float p10 = hn1 * w0, p11 = hn1 * w1;
            #pragma unroll
            for (int off = 32; off >= 1; off >>= 1) {
                p00 += __shfl_xor(p00, off);
                p01 += __shfl_xor(p01, off);
                p10 += __shfl_xor(p10, off);
                p11 += __shfl_xor(p11, off);
            }
            if (hid == 0) {
                float mk0 = sMask[t][m0], mk1 = sMask[t][m1];
                float o00 = (p00 + sBout[0]) * mk0, o01 = (p01 + sBout[1]) * mk0;
                float o10 = (p10 + sBout[0]) * mk1, o11 = (p11 + sBout[1]) * mk1;
                p.out[(t * N_AG + wbase + m0) * 2 + 0] = o00;
                p.out[(t * N_AG + wbase + m0) * 2 + 1] = o01;
                p.out[(t * N_AG + wbase + m1) * 2 + 0] = o10;
                p.out[(t * N_AG + wbase + m1) * 2 + 1] = o11;
                olocal[t & 1][m0][0] = o00; olocal[t & 1][m0][1] = o01;
                olocal[t & 1][m1][0] = o10; olocal[t & 1][m1][1] = o11;
            }
        }
        __syncthreads();   // bar4: hs + olocal stable before next step
    }
}

// ---------------------------------------------------------------------------
extern "C" void kernel_launch(void* const* d_in, const int* in_sizes, int n_in,
                              void* d_out, int out_size, void* d_ws, size_t ws_size,
                              hipStream_t stream)
{
    KP kp;
    kp.X     = (const float*)d_in[0];
    kp.masks = (const float*)d_in[1];
    kp.h_in  = (const float*)d_in[2];
    kp.c_in  = (const float*)d_in[3];
    // d_in[4] = Y (unused), d_in[5] = T_obs (=9), d_in[6] = T_pred (=19)
    kp.Win   = (const float*)d_in[7];
    kp.bin   = (const float*)d_in[8];
    const float* Wsoc = (const float*)d_in[9];
    kp.bsoc  = (const float*)d_in[10];
    kp.Wih   = (const float*)d_in[11];
    kp.Whh   = (const float*)d_in[12];
    kp.bih   = (const float*)d_in[13];
    kp.bhh   = (const float*)d_in[14];
    kp.Wout  = (const float*)d_in[15];
    kp.bout  = (const float*)d_in[16];
    kp.out   = (float*)d_out;

    unsigned long long* hist = (unsigned long long*)d_ws;   // 19*2048*64 (8B each)
    float* Wef = (float*)(hist + 19 * N_AG * 64);           // 4096
    int*   need = (int*)(Wef + 4096);                       // 19*2048
    int*   mcnt = need + 19 * N_AG;                         // 20*2048
    int*   midx = mcnt + STEPS * N_AG;                      // 20*2048*CAP

    kp.hist = hist; kp.Wef = Wef; kp.need = need; kp.mcnt = mcnt; kp.midx = midx;

    k_pre<<<53, 512, 0, stream>>>(kp.X, kp.masks, Wsoc, Wef, mcnt, midx, need,
                                  kp.out + 20 * N_AG * 2);

    k_persist<<<128, 512, 0, stream>>>(kp);
}